// Round 8
// baseline (89.517 us; speedup 1.0000x reference)
//
#include <hip/hip_runtime.h>
#include <float.h>

#define POOL 7
#define FW 2048
#define FH 2048
#define CROP 96
#define LROW 100   // floats per LDS row = 25 float4 EXACTLY -> LDS addr = 16*v (contiguous, DMA-compatible)

// async global->LDS DMA, 16B per lane, wave-uniform LDS base + lane*16
#define GLD16(gp, lp) __builtin_amdgcn_global_load_lds( \
    (const __attribute__((address_space(1))) void*)(gp), \
    (__attribute__((address_space(3))) void*)(lp), 16, 0, 0)

// Kernel 0: L3-warming sweep. The harness's 268 MB ws re-poison evicts L2+L3
// every timed iteration, leaving the feature map cold; the main kernel's
// scattered ~228 B row segments then run at ~750 GB/s DRAM efficiency.
// A coalesced linear read of the whole 33.5 MB map (5.3 us at 6.3 TB/s)
// re-warms L3 so the scattered phase hits cache. Per-thread checksum is
// stored to ws (re-poisoned anyway) so loads cannot be eliminated.
__global__ __launch_bounds__(256) void l3_warm_kernel(
    const float4* __restrict__ f, float* __restrict__ ws, int nvec)
{
    const int idx = blockIdx.x * blockDim.x + threadIdx.x;
    const int stride = gridDim.x * blockDim.x;
    float acc = 0.f;
    for (int v = idx; v < nvec; v += stride) {
        const float4 x = f[v];
        acc += x.x + x.y + x.z + x.w;
    }
    ws[idx] = acc;   // keep the loads live; ws is scratch
}

// Kernel 1 (unchanged R6 structure): one block per box.
//  ch0 window DMA'd straight to LDS, ch1 issued into regs immediately after.
//  Bin-max from LDS (4 lanes/output row-split + shfl combine), runtime bounds.
//  98->4 FC (32 lanes/output, prefetched weights) + ReLU + add into boxes row.
__global__ __launch_bounds__(256, 4) void roi_pool_fc_kernel(
    const float* __restrict__ feature,   // [2, 2048, 2048]
    const float* __restrict__ boxes,     // [N, 6]
    const int*   __restrict__ coords,    // [N, 4] (y1, x1, y2, x2)
    const float* __restrict__ fc_w,      // [4, 98]
    const float* __restrict__ fc_b,      // [4]
    float* __restrict__ out,             // [N, 6]
    int N)
{
    const int n = blockIdx.x;
    const int t = threadIdx.x;

    __shared__ float lds[CROP * LROW];   // 38,400 B -> 4 blocks/CU
    __shared__ float pooled[98];         // channel-major: c*49 + i*7 + j
    __shared__ float delta[4];

    const int4 cd = ((const int4*)coords)[n];   // uniform -> s_load
    const int y1 = cd.x;
    const int x1 = cd.y;
    const int h  = cd.z - y1;   // 7 <= h <= 96
    const int w  = cd.w - x1;   // 7 <= w <= 96

    const int x1a  = x1 & ~3;              // 16B-aligned window start
    const int off  = x1 - x1a;             // 0..3
    const int wvec = (w + off + 3) >> 2;   // float4 groups needed per row (<=25)

    // small prefetches (cheap; hidden under the staging window)
    float wpre[4] = {0.f, 0.f, 0.f, 0.f};
    float bias = 0.f;
    if (t < 128) {
        const int oo = t >> 5, lane = t & 31;
        const float* wrow = fc_w + oo * 98;
        #pragma unroll
        for (int k = 0; k < 4; ++k) {
            const int idx = lane + 32 * k;
            if (idx < 98) wpre[k] = wrow[idx];
        }
        if (lane == 0) bias = fc_b[oo];
    }
    const float bx = (t < 6) ? boxes[n * 6 + t] : 0.f;

    // ---- staging: up to 96 rows x 25 vec4 = 2400 vec4s; 10 chunks of 256 lanes.
    const float* b0 = feature + (size_t)y1 * FW + x1a;   // ch0
    const float* b1 = b0 + (size_t)FH * FW;              // ch1
    const int wbase = t & 192;                           // wave_id*64

    int   goff[10];
    bool  vok[10];
    #pragma unroll
    for (int k = 0; k < 10; ++k) {
        const int v = t + k * 256;
        const int r = v / 25;               // const-div -> magic mul
        const int c4 = v - r * 25;
        goff[k] = r * FW + 4 * c4;          // float offset into window
        vok[k]  = (v < 2400) && (r < h) && (c4 < wvec);
    }

    // ch0: async DMA straight into LDS (LDS addr = 16*v, wave-uniform base + lane*16)
    #pragma unroll
    for (int k = 0; k < 10; ++k) {
        char* lbase = (char*)lds + 16 * (wbase + k * 256);
        if (vok[k]) GLD16(b0 + goff[k], lbase);
    }
    // ch1: issue immediately -> both channels' windows in flight concurrently
    float4 regs[10];
    #pragma unroll
    for (int k = 0; k < 10; ++k)
        regs[k] = vok[k] ? *(const float4*)(b1 + goff[k])
                         : make_float4(0.f, 0.f, 0.f, 0.f);

    // compute-phase mapping: t -> (output o, row-split slot s)
    const int o = t >> 2;           // 0..48 for t < 196
    const int s = t & 3;
    const int i = o / 7;
    const int j = o % 7;
    int sr = 0, er = 0, sc = 0, ec = 0, sc4 = 0, ec4 = 0;
    if (t < 196) {
        sr  = (i * h) / POOL;
        er  = ((i + 1) * h + POOL - 1) / POOL;          // er <= h
        sc  = (j * w) / POOL + off;
        ec  = ((j + 1) * w + POOL - 1) / POOL + off;    // ec <= 4*wvec
        sc4 = sc >> 2;
        ec4 = (ec + 3) >> 2;                            // reads stay < wvec (staged)
    }

    __syncthreads();   // drains DMA (vmcnt) + all lanes ready

    // Phase 1: bin max ch0 from LDS
    if (t < 196) {
        float m = -FLT_MAX;
        for (int r = sr + s; r < er; r += 4) {
            const float4* rowp = (const float4*)(lds + r * LROW);
            for (int c4 = sc4; c4 < ec4; ++c4) {
                const float4 v = rowp[c4];
                const int b = c4 * 4;
                m = fmaxf(m, (b + 0 >= sc && b + 0 < ec) ? v.x : -FLT_MAX);
                m = fmaxf(m, (b + 1 >= sc && b + 1 < ec) ? v.y : -FLT_MAX);
                m = fmaxf(m, (b + 2 >= sc && b + 2 < ec) ? v.z : -FLT_MAX);
                m = fmaxf(m, (b + 3 >= sc && b + 3 < ec) ? v.w : -FLT_MAX);
            }
        }
        m = fmaxf(m, __shfl_xor(m, 1, 64));
        m = fmaxf(m, __shfl_xor(m, 2, 64));
        if (s == 0) pooled[o] = m;
    }
    __syncthreads();   // ch0 LDS reads done before overwrite

    // ch1 regs -> LDS (data long since landed)
    #pragma unroll
    for (int k = 0; k < 10; ++k)
        if (vok[k]) *(float4*)((char*)lds + 16 * (t + k * 256)) = regs[k];
    __syncthreads();

    // Phase 2: bin max ch1
    if (t < 196) {
        float m = -FLT_MAX;
        for (int r = sr + s; r < er; r += 4) {
            const float4* rowp = (const float4*)(lds + r * LROW);
            for (int c4 = sc4; c4 < ec4; ++c4) {
                const float4 v = rowp[c4];
                const int b = c4 * 4;
                m = fmaxf(m, (b + 0 >= sc && b + 0 < ec) ? v.x : -FLT_MAX);
                m = fmaxf(m, (b + 1 >= sc && b + 1 < ec) ? v.y : -FLT_MAX);
                m = fmaxf(m, (b + 2 >= sc && b + 2 < ec) ? v.z : -FLT_MAX);
                m = fmaxf(m, (b + 3 >= sc && b + 3 < ec) ? v.w : -FLT_MAX);
            }
        }
        m = fmaxf(m, __shfl_xor(m, 1, 64));
        m = fmaxf(m, __shfl_xor(m, 2, 64));
        if (s == 0) pooled[49 + o] = m;
    }
    __syncthreads();

    // Phase 3: FC (98 -> 4), 32 lanes per output, prefetched weights
    if (t < 128) {
        const int lane = t & 31;
        float acc = 0.f;
        #pragma unroll
        for (int k = 0; k < 4; ++k) {
            const int idx = lane + 32 * k;
            acc = fmaf(idx < 98 ? pooled[idx] : 0.f, wpre[k], acc);
        }
        #pragma unroll
        for (int mm = 16; mm; mm >>= 1)
            acc += __shfl_xor(acc, mm, 64);   // masks <32 stay within 32-lane group
        if (lane == 0) delta[t >> 5] = fmaxf(acc + bias, 0.f);
    }
    __syncthreads();

    if (t < 6)
        out[n * 6 + t] = bx + (t >= 2 ? delta[t - 2] : 0.f);
}

extern "C" void kernel_launch(void* const* d_in, const int* in_sizes, int n_in,
                              void* d_out, int out_size, void* d_ws, size_t ws_size,
                              hipStream_t stream) {
    const float* feature = (const float*)d_in[0];  // [1,2,2048,2048] fp32
    const float* boxes   = (const float*)d_in[1];  // [N,6] fp32
    const int*   coords  = (const int*)d_in[2];    // [N,4] int32
    const float* fc_w    = (const float*)d_in[3];  // [4,98] fp32
    const float* fc_b    = (const float*)d_in[4];  // [4] fp32
    float* out = (float*)d_out;                    // [N,6] fp32

    const int N = in_sizes[2] / 4;

    // Warm L3 with a coalesced pass over the feature map (stream-ordered
    // before the main kernel). 1024 blocks x 256 thr, 8 float4 per thread.
    const int nvec = in_sizes[0] / 4;   // 2*2048*2048/4 float4s
    l3_warm_kernel<<<1024, 256, 0, stream>>>((const float4*)feature, (float*)d_ws, nvec);

    roi_pool_fc_kernel<<<N, 256, 0, stream>>>(feature, boxes, coords, fc_w, fc_b, out, N);
}

// Round 9
// 83.209 us; speedup vs baseline: 1.0758x; 1.0758x over previous
//
#include <hip/hip_runtime.h>
#include <float.h>

#define POOL 7
#define FW 2048
#define FH 2048
#define CROP 96
#define LROW 100   // floats per LDS row = 25 float4 EXACTLY -> LDS addr = 16*v (contiguous, DMA-compatible)

// async global->LDS DMA, 16B per lane, wave-uniform LDS base + lane*16
#define GLD16(gp, lp) __builtin_amdgcn_global_load_lds( \
    (const __attribute__((address_space(1))) void*)(gp), \
    (__attribute__((address_space(3))) void*)(lp), 16, 0, 0)

// One block per box. Both channels staged via global_load_lds DMA (no VGPR
// staging arrays -> low pressure). Bin-max: row loop rolled (<=4 iters), col
// dimension UNROLLED x5 -> 5 independent ds_read_b128 in flight, ONE lgkmcnt
// wait per row-iter (vs 20 serialized ~120cyc waits in R4). Element masking
// via precomputed sel floats: fmaxf(m, fminf(v, sel)), sel = in-bin ? +MAX :
// -MAX (v_min returns non-NaN operand, so stale LDS garbage is safe).
// 98->4 FC (32 lanes/output, prefetched weights) + ReLU + add into boxes row.
__global__ __launch_bounds__(256, 4) void roi_pool_fc_kernel(
    const float* __restrict__ feature,   // [2, 2048, 2048]
    const float* __restrict__ boxes,     // [N, 6]
    const int*   __restrict__ coords,    // [N, 4] (y1, x1, y2, x2)
    const float* __restrict__ fc_w,      // [4, 98]
    const float* __restrict__ fc_b,      // [4]
    float* __restrict__ out,             // [N, 6]
    int N)
{
    const int n = blockIdx.x;
    const int t = threadIdx.x;

    __shared__ float lds[CROP * LROW + 8];   // +8: 5-group unroll over-read at row 95
    __shared__ float pooled[98];             // channel-major: c*49 + i*7 + j
    __shared__ float delta[4];

    const int4 cd = ((const int4*)coords)[n];   // uniform -> s_load
    const int y1 = cd.x;
    const int x1 = cd.y;
    const int h  = cd.z - y1;   // 7 <= h <= 96
    const int w  = cd.w - x1;   // 7 <= w <= 96

    const int x1a  = x1 & ~3;              // 16B-aligned window start
    const int off  = x1 - x1a;             // 0..3
    const int wvec = (w + off + 3) >> 2;   // float4 groups needed per row (<=25)

    // small prefetches (hidden under the DMA window)
    float wpre[4] = {0.f, 0.f, 0.f, 0.f};
    float bias = 0.f;
    if (t < 128) {
        const int oo = t >> 5, lane = t & 31;
        const float* wrow = fc_w + oo * 98;
        #pragma unroll
        for (int k = 0; k < 4; ++k) {
            const int idx = lane + 32 * k;
            if (idx < 98) wpre[k] = wrow[idx];
        }
        if (lane == 0) bias = fc_b[oo];
    }
    const float bx = (t < 6) ? boxes[n * 6 + t] : 0.f;

    // ---- staging geometry: up to 96 rows x 25 vec4 = 2400 vec4s; 10 x 256
    const float* b0 = feature + (size_t)y1 * FW + x1a;   // ch0
    const float* b1 = b0 + (size_t)FH * FW;              // ch1
    const int wbase = t & 192;                           // wave_id*64

    int  goff[10];
    bool vok[10];
    #pragma unroll
    for (int k = 0; k < 10; ++k) {
        const int v = t + k * 256;
        const int r = v / 25;               // const-div -> magic mul
        const int c4 = v - r * 25;
        goff[k] = r * FW + 4 * c4;          // float offset into window
        vok[k]  = (v < 2400) && (r < h) && (c4 < wvec);
    }

    // ch0: async DMA straight into LDS (LDS addr = 16*v)
    #pragma unroll
    for (int k = 0; k < 10; ++k) {
        char* lbase = (char*)lds + 16 * (wbase + k * 256);
        if (vok[k]) GLD16(b0 + goff[k], lbase);
    }

    // ---- bin geometry + hoisted select masks (reused for both channels)
    const int o = t >> 2;           // 0..48 for t < 196
    const int s = t & 3;
    const int i = o / 7;
    const int j = o % 7;
    int sr = 0, er = 0, sc4 = 0;
    float sel[20];
    if (t < 196) {
        sr = (i * h) / POOL;
        er = ((i + 1) * h + POOL - 1) / POOL;              // er <= h <= 96
        const int sc = (j * w) / POOL + off;
        const int ec = ((j + 1) * w + POOL - 1) / POOL + off;   // ec - sc <= 14
        sc4 = sc >> 2;                                     // <= 21
        #pragma unroll
        for (int q = 0; q < 20; ++q) {
            const int b = sc4 * 4 + q;
            sel[q] = (b >= sc && b < ec) ? FLT_MAX : -FLT_MAX;
        }
    }

    // col-unrolled bin-max: 5 b128 in flight, one wait per row-iter
    auto binmax = [&]() -> float {
        float m = -FLT_MAX;
        for (int r = sr + s; r < er; r += 4) {             // <= 4 iters
            const float4* rowp = (const float4*)(lds + r * LROW + 4 * sc4);
            float4 v[5];
            #pragma unroll
            for (int q = 0; q < 5; ++q) v[q] = rowp[q];
            #pragma unroll
            for (int q = 0; q < 5; ++q) {
                m = fmaxf(m, fminf(v[q].x, sel[4 * q + 0]));
                m = fmaxf(m, fminf(v[q].y, sel[4 * q + 1]));
                m = fmaxf(m, fminf(v[q].z, sel[4 * q + 2]));
                m = fmaxf(m, fminf(v[q].w, sel[4 * q + 3]));
            }
        }
        m = fmaxf(m, __shfl_xor(m, 1, 64));                // 4 row-split lanes
        m = fmaxf(m, __shfl_xor(m, 2, 64));
        return m;
    };

    __syncthreads();   // drains ch0 DMA (compiler emits vmcnt(0) before barrier)

    float m0 = -FLT_MAX;
    if (t < 196) m0 = binmax();
    __syncthreads();   // ch0 LDS reads done before overwrite

    // ch1: DMA into same LDS
    #pragma unroll
    for (int k = 0; k < 10; ++k) {
        char* lbase = (char*)lds + 16 * (wbase + k * 256);
        if (vok[k]) GLD16(b1 + goff[k], lbase);
    }
    __syncthreads();   // drains ch1 DMA

    if (t < 196) {
        const float m1 = binmax();
        if (s == 0) { pooled[o] = m0; pooled[49 + o] = m1; }
    }
    __syncthreads();

    // ---- FC (98 -> 4), 32 lanes per output, prefetched weights
    if (t < 128) {
        const int lane = t & 31;
        float acc = 0.f;
        #pragma unroll
        for (int k = 0; k < 4; ++k) {
            const int idx = lane + 32 * k;
            acc = fmaf(idx < 98 ? pooled[idx] : 0.f, wpre[k], acc);
        }
        #pragma unroll
        for (int mm = 16; mm; mm >>= 1)
            acc += __shfl_xor(acc, mm, 64);   // masks <32 stay within 32-lane group
        if (lane == 0) delta[t >> 5] = fmaxf(acc + bias, 0.f);
    }
    __syncthreads();

    if (t < 6)
        out[n * 6 + t] = bx + (t >= 2 ? delta[t - 2] : 0.f);
}

extern "C" void kernel_launch(void* const* d_in, const int* in_sizes, int n_in,
                              void* d_out, int out_size, void* d_ws, size_t ws_size,
                              hipStream_t stream) {
    const float* feature = (const float*)d_in[0];  // [1,2,2048,2048] fp32
    const float* boxes   = (const float*)d_in[1];  // [N,6] fp32
    const int*   coords  = (const int*)d_in[2];    // [N,4] int32
    const float* fc_w    = (const float*)d_in[3];  // [4,98] fp32
    const float* fc_b    = (const float*)d_in[4];  // [4] fp32
    float* out = (float*)d_out;                    // [N,6] fp32

    const int N = in_sizes[2] / 4;
    roi_pool_fc_kernel<<<N, 256, 0, stream>>>(feature, boxes, coords, fc_w, fc_b, out, N);
}